// Round 24
// baseline (124.087 us; speedup 1.0000x reference)
//
#include <hip/hip_runtime.h>
#include <hip/hip_bf16.h>
#include <stdint.h>

using f32x16 = __attribute__((ext_vector_type(16))) float;
using short8 = __attribute__((ext_vector_type(8))) short;

#define C2LOG2E 2.8853900817779268f   // 2*log2(e)

static __device__ __forceinline__ unsigned cvt_pk_bf16(float lo, float hi) {
  unsigned r;
  asm("v_cvt_pk_bf16_f32 %0, %1, %2" : "=v"(r) : "v"(lo), "v"(hi));
  return r;
}

// butterfly add stage via DPP (VALU, no DS); ctrl is a template constant.
template <int CTRL>
static __device__ __forceinline__ float dpp_add(float v) {
  int x = __builtin_amdgcn_update_dpp(0, __float_as_int(v), CTRL, 0xF, 0xF, true);
  return v + __int_as_float(x);
}
#define DPP_XOR1 0xB1   // quad_perm [1,0,3,2]
#define DPP_XOR2 0x4E   // quad_perm [2,3,0,1]
#define DPP_XOR4 0x141  // row_half_mirror
#define DPP_XOR8 0x140  // row_mirror

// magic multipliers indexed by DIVISOR d (1..8): q = (rr * M[d]) >> 16, exact for rr<2^10
__device__ static const unsigned kMagicDiv[9] = {0u, 65536u, 32768u, 21846u, 16384u,
                                                 13108u, 10923u, 9363u, 8192u};

// ---------------------------------------------------------------- prep ------
// Pack Wp into bf16 MFMA frag layout; pack x into the SAME frag geometry but
// f32 (2 KB/block): dword(rc,kk) = ((kk>>3)*32 + rc)*8 + (kk&7).  k_scores
// multiplies x_n*x_m in native f32 and packs to bf16 with ONE cvt_pk
// (avoids hipcc's emulated bf16 __hmul2 — the A-build VALU tax).
// Block 0 also zeroes bnacc.
__global__ __launch_bounds__(256) void k_prep(const float* __restrict__ x,
                                              const float* __restrict__ Wp,
                                              float* __restrict__ xfragF,
                                              unsigned int* __restrict__ wpfrag,
                                              float* __restrict__ bnacc) {
  const int bid = blockIdx.x, t = threadIdx.x;
  if (bid == 0) {
    bnacc[t] = 0.f;
    bnacc[256 + t] = 0.f;
  }
  const int half = t >> 7, dpair = (t >> 5) & 3, rc = t & 31;
  const int kk = half * 8 + dpair * 2;
  if (bid < 1024) {
    const int b = bid >> 7, mt = (bid >> 4) & 7, ks = bid & 15;
    const int m = mt * 32 + rc;
    const int k = ks * 16 + kk;
    float2 v = *(const float2*)(x + (size_t)(b * 256 + m) * 256 + k);
    float* dst = xfragF + (size_t)b * 65536 + ((mt * 16 + ks) << 9)
               + half * 256 + rc * 8 + dpair * 2;
    dst[0] = v.x;
    dst[1] = v.y;
  } else {
    const int b2 = bid - 1024;                 // 0..127
    const int et = b2 >> 4, ks = b2 & 15;
    const int e = et * 32 + rc;
    const int k = ks * 16 + kk;
    float v0 = Wp[(size_t)k * 256 + e];
    float v1 = Wp[(size_t)(k + 1) * 256 + e];
    wpfrag[((et * 16 + ks) << 8) + half * 128 + rc * 4 + dpair] = cvt_pk_bf16(v0, v1);
  }
}

// --------------------------------------------------------------- scores -----
// R14 structure (72.5us plateau) with the A-build switched to native-f32
// multiply + single cvt_pk (12 VALU/ks vs ~32 emulated bf16 ops).
__global__ __launch_bounds__(512, 2) void k_scores(
    const float* __restrict__ xfragF, const unsigned int* __restrict__ wpfrag,
    const float* __restrict__ bp, const float* __restrict__ watt,
    float* __restrict__ sp) {
  __shared__ unsigned char wplds[131072];

  const int tid = threadIdx.x;
  const int l = tid & 63, w = tid >> 6;          // w in [0,8)
  const int c = l & 31, hi = l >> 5;

  // stage full Wp frag (128 KB) linearly, zero VALU (8 waves x 16 it x 1KB)
  {
    const unsigned char* src = (const unsigned char*)wpfrag;
    #pragma unroll
    for (int it = 0; it < 16; ++it) {
      __builtin_amdgcn_global_load_lds(
          (const __attribute__((address_space(1))) unsigned int*)(src + it * 8192 + w * 1024 + l * 16),
          (__attribute__((address_space(3))) unsigned int*)(&wplds[it * 8192 + w * 1024]),
          16, 0, 0);
    }
  }

  // per-lane epilogue constants: e = et*32 + c, et = 0..7
  float bpe[8], wm2[8], Wl = 0.f;
  #pragma unroll
  for (int et = 0; et < 8; ++et) {
    float bv = bp[et * 32 + c];
    float wv = watt[et * 32 + c];
    bpe[et] = bv * C2LOG2E;
    wm2[et] = -2.f * wv;
    Wl += wv;
  }
  __syncthreads();

  const int gw = blockIdx.x * 8 + w;   // 0..2047

  for (int i = gw; i < 9216; i += 2048) {
    // ---- decode item -> (b, n, mt)  (validated R5-R23) --------------------
    int b = i / 1152;
    int r = i - b * 1152;
    int nt, cum;
    if      (r < 256)  { nt = 0; cum = 0; }
    else if (r < 480)  { nt = 1; cum = 256; }
    else if (r < 672)  { nt = 2; cum = 480; }
    else if (r < 832)  { nt = 3; cum = 672; }
    else if (r < 960)  { nt = 4; cum = 832; }
    else if (r < 1056) { nt = 5; cum = 960; }
    else               { nt = (r < 1120) ? 6 : 7; cum = (r < 1120) ? 1056 : 1120; }
    int rr = r - cum;
    int w8 = 8 - nt;                                       // divisor, 1..8
    int q0 = (int)(((unsigned)rr * kMagicDiv[w8]) >> 16);  // rr / w8
    int n  = nt * 32 + q0;
    int mt = nt + (rr - q0 * w8);                          // in [nt, 8)
    const int m0 = mt * 32;

    const unsigned char* xfb = (const unsigned char*)xfragF + (size_t)b * 262144;
    const unsigned char* xnbase = xfb + (nt << 15) + hi * 1024 + q0 * 32;
    const unsigned char* xmbase = xfb + (mt << 15) + (l >> 5) * 1024 + (l & 31) * 32;

    // ---- full-e accumulation: acc[8] f32x16 (128 AGPR) --------------------
    f32x16 acc[8];
    #pragma unroll
    for (int et = 0; et < 8; ++et)
      #pragma unroll
      for (int q = 0; q < 16; ++q) acc[et][q] = 0.f;

    #pragma unroll 2
    for (int ks = 0; ks < 16; ++ks) {
      // transient A-frag: (x_n * x_m) in f32, packed once to bf16
      float4 xm0 = *(const float4*)(xmbase + (ks << 11));
      float4 xm1 = *(const float4*)(xmbase + (ks << 11) + 16);
      float4 xn0 = *(const float4*)(xnbase + (ks << 11));
      float4 xn1 = *(const float4*)(xnbase + (ks << 11) + 16);
      union { unsigned u[4]; short8 s; } a;
      a.u[0] = cvt_pk_bf16(xm0.x * xn0.x, xm0.y * xn0.y);
      a.u[1] = cvt_pk_bf16(xm0.z * xn0.z, xm0.w * xn0.w);
      a.u[2] = cvt_pk_bf16(xm1.x * xn1.x, xm1.y * xn1.y);
      a.u[3] = cvt_pk_bf16(xm1.z * xn1.z, xm1.w * xn1.w);

      #pragma unroll
      for (int et = 0; et < 8; ++et) {
        short8 bf = *(const short8*)(&wplds[((et * 16 + ks) << 10) + l * 16]);
        acc[et] = __builtin_amdgcn_mfma_f32_32x32x16_bf16(a.s, bf, acc[et], 0, 0, 0);
      }
    }

    // ---- epilogue: p[m] = Wl + sum_et wm2*rcp(1+exp2(acc*C + bpe)) --------
    float p[16];
    #pragma unroll
    for (int q = 0; q < 16; ++q) {
      float pq = Wl;
      #pragma unroll
      for (int et = 0; et < 8; ++et) {
        float v = fmaf(acc[et][q], C2LOG2E, bpe[et]);
        pq = fmaf(wm2[et], __builtin_amdgcn_rcpf(1.f + exp2f(v)), pq);
      }
      p[q] = pq;
    }

    // ---- reduce over 32 e-cols: 4 DPP stages + 1 shfl ---------------------
    #pragma unroll
    for (int q = 0; q < 16; ++q) {
      float v = p[q];
      v = dpp_add<DPP_XOR1>(v);
      v = dpp_add<DPP_XOR2>(v);
      v = dpp_add<DPP_XOR4>(v);
      v = dpp_add<DPP_XOR8>(v);
      v += __shfl_xor(v, 16);
      p[q] = v;
    }
    if (c == 0) {
      float* outrow = sp + (size_t)(b * 256 + n) * 256 + m0;
      #pragma unroll
      for (int q = 0; q < 16; ++q) {
        int mr = (q & 3) + 8 * (q >> 2) + 4 * hi;
        outrow[mr] = p[q];
      }
      if (mt > nt) {
        #pragma unroll
        for (int q = 0; q < 16; ++q) {
          int mr = (q & 3) + 8 * (q >> 2) + 4 * hi;
          sp[(size_t)(b * 256 + m0 + mr) * 256 + n] = p[q];
        }
      }
    }
  }
}

// -------------------------------------------------------------- colstats ----
// Per-(b,m) column max M and 1/sum(exp(s-M)) over n.
__global__ __launch_bounds__(256) void k_colstats(const float* __restrict__ sp,
                                                  float* __restrict__ colM,
                                                  float* __restrict__ colInv) {
  __shared__ float tile[256][33];
  __shared__ float red[8][32];
  const int t = threadIdx.x;
  const int bb = blockIdx.x >> 3, mt = blockIdx.x & 7;
  const int m0 = mt * 32;
  const int col = t & 31, g = t >> 5;   // g in [0,8)

  for (int cc = 0; cc < 32; ++cc) {
    int nn = cc * 8 + g;
    tile[nn][col] = sp[(size_t)(bb * 256 + nn) * 256 + m0 + col];
  }
  __syncthreads();
  float mx = -1e30f;
  for (int k2 = 0; k2 < 32; ++k2) mx = fmaxf(mx, tile[g * 32 + k2][col]);
  red[g][col] = mx;
  __syncthreads();
  float M = red[0][col];
  #pragma unroll
  for (int j = 1; j < 8; ++j) M = fmaxf(M, red[j][col]);
  float sm = 0.f;
  for (int k2 = 0; k2 < 32; ++k2) sm += __expf(tile[g * 32 + k2][col] - M);
  __syncthreads();
  red[g][col] = sm;
  __syncthreads();
  if (g == 0) {
    float S = red[0][col];
    #pragma unroll
    for (int j = 1; j < 8; ++j) S += red[j][col];
    colM[bb * 256 + m0 + col]   = M;
    colInv[bb * 256 + m0 + col] = 1.0f / S;
  }
}

// -------------------------------------------------------------- aggproj -----
// R18's validated 8-row structure.  att computed on the fly:
// att[n,m] = exp(sp[n,m]-M_m)*inv_m.  BN partials into bnacc via atomics
// (terminal reduction only — R20 lesson).
__global__ __launch_bounds__(256) void k_aggproj(
    const float* __restrict__ x, const float* __restrict__ spRaw,
    const float* __restrict__ colM, const float* __restrict__ colInv,
    const float* __restrict__ W1, const float* __restrict__ b1,
    const float* __restrict__ W2, const float* __restrict__ b2,
    float* __restrict__ out, float* __restrict__ bnacc) {
  __shared__ float att8[8][256];
  __shared__ float xn8[8][256];
  __shared__ float agg8[8][256];
  const int t = threadIdx.x;
  const int bb = blockIdx.x >> 5, ng = blockIdx.x & 31;
  const int n0 = ng * 8;

  const float cm = colM[bb * 256 + t];
  const float ci = colInv[bb * 256 + t];
  #pragma unroll
  for (int i = 0; i < 8; ++i) {
    float s = spRaw[(size_t)(bb * 256 + n0 + i) * 256 + t];
    att8[i][t] = __expf(s - cm) * ci;
    xn8[i][t]  = x[(size_t)(bb * 256 + n0 + i) * 256 + t];
  }
  __syncthreads();

  float ar[8] = {0.f, 0.f, 0.f, 0.f, 0.f, 0.f, 0.f, 0.f};
  for (int m4 = 0; m4 < 64; ++m4) {
    int m = m4 * 4;
    float xv0 = x[(size_t)(bb * 256 + m + 0) * 256 + t];
    float xv1 = x[(size_t)(bb * 256 + m + 1) * 256 + t];
    float xv2 = x[(size_t)(bb * 256 + m + 2) * 256 + t];
    float xv3 = x[(size_t)(bb * 256 + m + 3) * 256 + t];
    #pragma unroll
    for (int i = 0; i < 8; ++i) {
      float4 av = *(const float4*)&att8[i][m];
      ar[i] += av.x * xv0 + av.y * xv1 + av.z * xv2 + av.w * xv3;
    }
  }
  #pragma unroll
  for (int i = 0; i < 8; ++i) agg8[i][t] = ar[i];
  __syncthreads();

  float o[8];
  float bsum = b1[t] + b2[t];
  #pragma unroll
  for (int i = 0; i < 8; ++i) o[i] = bsum;
  for (int d4 = 0; d4 < 64; ++d4) {
    int d = d4 * 4;
    float w10 = W1[(d + 0) * 256 + t], w11 = W1[(d + 1) * 256 + t];
    float w12 = W1[(d + 2) * 256 + t], w13 = W1[(d + 3) * 256 + t];
    float w20 = W2[(d + 0) * 256 + t], w21 = W2[(d + 1) * 256 + t];
    float w22 = W2[(d + 2) * 256 + t], w23 = W2[(d + 3) * 256 + t];
    #pragma unroll
    for (int i = 0; i < 8; ++i) {
      float4 ag = *(const float4*)&agg8[i][d];
      float4 xn = *(const float4*)&xn8[i][d];
      o[i] += ag.x * w10 + ag.y * w11 + ag.z * w12 + ag.w * w13
            + xn.x * w20 + xn.y * w21 + xn.z * w22 + xn.w * w23;
    }
  }
  float s1 = 0.f, s2 = 0.f;
  #pragma unroll
  for (int i = 0; i < 8; ++i) {
    out[(size_t)(bb * 256 + n0 + i) * 256 + t] = o[i];
    s1 += o[i];
    s2 += o[i] * o[i];
  }
  atomicAdd(&bnacc[t], s1);
  atomicAdd(&bnacc[256 + t], s2);
}

// -------------------------------------------------------------- bnapply -----
// grid 2048: one row per block, max TLP on a stream-bound kernel.
__global__ __launch_bounds__(256) void k_bnapply(float* __restrict__ io,
                                                 const float* __restrict__ bnacc,
                                                 const float* __restrict__ gamma,
                                                 const float* __restrict__ beta) {
  const int e = threadIdx.x;
  float mean = bnacc[e] * (1.0f / 2048.0f);
  float var  = bnacc[256 + e] * (1.0f / 2048.0f) - mean * mean;
  float scl  = rsqrtf(var + 1e-5f) * gamma[e];
  float sh   = beta[e] - mean * scl;
  for (int r = blockIdx.x; r < 2048; r += gridDim.x) {
    float v = io[(size_t)r * 256 + e];
    float y = v * scl + sh;
    float s = (y > 0.f) ? 1.0507009873554805f * y
                        : 1.7580993408473766f * (__expf(y) - 1.0f);
    io[(size_t)r * 256 + e] = s;
  }
}

// ---------------------------------------------------------------------------
extern "C" void kernel_launch(void* const* d_in, const int* in_sizes, int n_in,
                              void* d_out, int out_size, void* d_ws, size_t ws_size,
                              hipStream_t stream) {
  const float* x     = (const float*)d_in[0];
  const float* Wp    = (const float*)d_in[1];
  const float* bp    = (const float*)d_in[2];
  const float* watt  = (const float*)d_in[3];
  const float* W1    = (const float*)d_in[4];
  const float* b1    = (const float*)d_in[5];
  const float* W2    = (const float*)d_in[6];
  const float* b2    = (const float*)d_in[7];
  const float* gamma = (const float*)d_in[8];
  const float* beta  = (const float*)d_in[9];
  float* out = (float*)d_out;
  float* ws  = (float*)d_ws;

  float* sp = ws;                                       // 524288 f32 raw scores
  unsigned int* wpfragG = (unsigned int*)(ws + 524288); // 32768 dwords (128 KB)
  float* xfragF = (float*)(wpfragG + 32768);            // 524288 f32 (2 MB)
  float* bnacc  = xfragF + 524288;                      // 512 f32
  float* colM   = bnacc + 512;                          // 2048 f32
  float* colInv = colM + 2048;                          // 2048 f32

  k_prep    <<<1152, 256, 0, stream>>>(x, Wp, xfragF, wpfragG, bnacc);
  k_scores  <<<256,  512, 0, stream>>>(xfragF, wpfragG, bp, watt, sp);
  k_colstats<<<64,   256, 0, stream>>>(sp, colM, colInv);
  k_aggproj <<<256,  256, 0, stream>>>(x, sp, colM, colInv, W1, b1, W2, b2, out, bnacc);
  k_bnapply <<<2048, 256, 0, stream>>>(out, bnacc, gamma, beta);
}

// Round 25
// 118.700 us; speedup vs baseline: 1.0454x; 1.0454x over previous
//
#include <hip/hip_runtime.h>
#include <hip/hip_bf16.h>
#include <stdint.h>

using f32x16 = __attribute__((ext_vector_type(16))) float;
using short8 = __attribute__((ext_vector_type(8))) short;

#define C2LOG2E 2.8853900817779268f   // 2*log2(e)

static __device__ __forceinline__ unsigned cvt_pk_bf16(float lo, float hi) {
  unsigned r;
  asm("v_cvt_pk_bf16_f32 %0, %1, %2" : "=v"(r) : "v"(lo), "v"(hi));
  return r;
}

// butterfly add stage via DPP (VALU, no DS); ctrl is a template constant.
template <int CTRL>
static __device__ __forceinline__ float dpp_add(float v) {
  int x = __builtin_amdgcn_update_dpp(0, __float_as_int(v), CTRL, 0xF, 0xF, true);
  return v + __int_as_float(x);
}
#define DPP_XOR1 0xB1   // quad_perm [1,0,3,2]
#define DPP_XOR2 0x4E   // quad_perm [2,3,0,1]
#define DPP_XOR4 0x141  // row_half_mirror
#define DPP_XOR8 0x140  // row_mirror

// magic multipliers indexed by DIVISOR d (1..8): q = (rr * M[d]) >> 16, exact for rr<2^10
__device__ static const unsigned kMagicDiv[9] = {0u, 65536u, 32768u, 21846u, 16384u,
                                                 13108u, 10923u, 9363u, 8192u};

// ---------------------------------------------------------------- prep ------
// Pack x and Wp into 32x32x16-MFMA fragment-linear bf16 layouts; block 0 also
// zeroes bnacc (aggproj accumulates BN stats there via atomics; prep completes
// before aggproj launches, so ordering is guaranteed).
__global__ __launch_bounds__(256) void k_prep(const float* __restrict__ x,
                                              const float* __restrict__ Wp,
                                              unsigned int* __restrict__ xfrag,
                                              unsigned int* __restrict__ wpfrag,
                                              float* __restrict__ bnacc) {
  const int bid = blockIdx.x, t = threadIdx.x;
  if (bid == 0) {
    bnacc[t] = 0.f;
    bnacc[256 + t] = 0.f;
  }
  const int half = t >> 7, dpair = (t >> 5) & 3, rc = t & 31;
  const int kk = half * 8 + dpair * 2;
  if (bid < 1024) {
    const int b = bid >> 7, mt = (bid >> 4) & 7, ks = bid & 15;
    const int m = mt * 32 + rc;
    const int k = ks * 16 + kk;
    float2 v = *(const float2*)(x + (size_t)(b * 256 + m) * 256 + k);
    xfrag[(size_t)b * 32768 + ((mt * 16 + ks) << 8) + half * 128 + rc * 4 + dpair] =
        cvt_pk_bf16(v.x, v.y);
  } else {
    const int b2 = bid - 1024;                 // 0..127
    const int et = b2 >> 4, ks = b2 & 15;
    const int e = et * 32 + rc;
    const int k = ks * 16 + kk;
    float v0 = Wp[(size_t)k * 256 + e];
    float v1 = Wp[(size_t)(k + 1) * 256 + e];
    wpfrag[((et * 16 + ks) << 8) + half * 128 + rc * 4 + dpair] = cvt_pk_bf16(v0, v1);
  }
}

// --------------------------------------------------------------- scores -----
// R14 structure — the 10-times-probed 72.5us equilibrium.  bf16 frags (R24:
// f32 frags cut VALU but lengthened the VMEM chain, net loss).  Atomics OUT
// (R20); no cooperative sync (R22).
__global__ __launch_bounds__(512, 2) void k_scores(
    const unsigned int* __restrict__ xfrag, const unsigned int* __restrict__ wpfrag,
    const float* __restrict__ bp, const float* __restrict__ watt,
    float* __restrict__ sp) {
  __shared__ unsigned char wplds[131072];

  const int tid = threadIdx.x;
  const int l = tid & 63, w = tid >> 6;          // w in [0,8)
  const int c = l & 31, hi = l >> 5;

  // stage full Wp frag (128 KB) linearly, zero VALU (8 waves x 16 it x 1KB)
  {
    const unsigned char* src = (const unsigned char*)wpfrag;
    #pragma unroll
    for (int it = 0; it < 16; ++it) {
      __builtin_amdgcn_global_load_lds(
          (const __attribute__((address_space(1))) unsigned int*)(src + it * 8192 + w * 1024 + l * 16),
          (__attribute__((address_space(3))) unsigned int*)(&wplds[it * 8192 + w * 1024]),
          16, 0, 0);
    }
  }

  // per-lane epilogue constants: e = et*32 + c, et = 0..7
  float bpe[8], wm2[8], Wl = 0.f;
  #pragma unroll
  for (int et = 0; et < 8; ++et) {
    float bv = bp[et * 32 + c];
    float wv = watt[et * 32 + c];
    bpe[et] = bv * C2LOG2E;
    wm2[et] = -2.f * wv;
    Wl += wv;
  }
  __syncthreads();

  const int gw = blockIdx.x * 8 + w;   // 0..2047

  for (int i = gw; i < 9216; i += 2048) {
    // ---- decode item -> (b, n, mt)  (validated R5-R24) --------------------
    int b = i / 1152;
    int r = i - b * 1152;
    int nt, cum;
    if      (r < 256)  { nt = 0; cum = 0; }
    else if (r < 480)  { nt = 1; cum = 256; }
    else if (r < 672)  { nt = 2; cum = 480; }
    else if (r < 832)  { nt = 3; cum = 672; }
    else if (r < 960)  { nt = 4; cum = 832; }
    else if (r < 1056) { nt = 5; cum = 960; }
    else               { nt = (r < 1120) ? 6 : 7; cum = (r < 1120) ? 1056 : 1120; }
    int rr = r - cum;
    int w8 = 8 - nt;                                       // divisor, 1..8
    int q0 = (int)(((unsigned)rr * kMagicDiv[w8]) >> 16);  // rr / w8
    int n  = nt * 32 + q0;
    int mt = nt + (rr - q0 * w8);                          // in [nt, 8)
    const int m0 = mt * 32;

    const unsigned char* xfb = (const unsigned char*)xfrag + (size_t)b * 131072;
    const unsigned char* xnbase = xfb + (nt << 14) + hi * 512 + q0 * 16;
    const unsigned char* xmbase = xfb + (mt << 14) + l * 16;

    // ---- full-e accumulation: acc[8] f32x16 (128 AGPR) --------------------
    f32x16 acc[8];
    #pragma unroll
    for (int et = 0; et < 8; ++et)
      #pragma unroll
      for (int q = 0; q < 16; ++q) acc[et][q] = 0.f;

    #pragma unroll 2
    for (int ks = 0; ks < 16; ++ks) {
      // transient A-frag: (x_n ∘ x_m) built per k-step, ONCE per item
      uint4 xnp = *(const uint4*)(xnbase + (ks << 10));
      uint4 xm  = *(const uint4*)(xmbase + (ks << 10));
      union U { uint4 u; short8 s; __hip_bfloat162 hh[4]; } a, mm, nn;
      mm.u = xm; nn.u = xnp;
      #pragma unroll
      for (int d = 0; d < 4; ++d) a.hh[d] = __hmul2(mm.hh[d], nn.hh[d]);

      #pragma unroll
      for (int et = 0; et < 8; ++et) {
        short8 bf = *(const short8*)(&wplds[((et * 16 + ks) << 10) + l * 16]);
        acc[et] = __builtin_amdgcn_mfma_f32_32x32x16_bf16(a.s, bf, acc[et], 0, 0, 0);
      }
    }

    // ---- epilogue: p[m] = Wl + sum_et wm2*rcp(1+exp2(acc*C + bpe)) --------
    float p[16];
    #pragma unroll
    for (int q = 0; q < 16; ++q) {
      float pq = Wl;
      #pragma unroll
      for (int et = 0; et < 8; ++et) {
        float v = fmaf(acc[et][q], C2LOG2E, bpe[et]);
        pq = fmaf(wm2[et], __builtin_amdgcn_rcpf(1.f + exp2f(v)), pq);
      }
      p[q] = pq;
    }

    // ---- reduce over 32 e-cols: 4 DPP stages + 1 shfl ---------------------
    #pragma unroll
    for (int q = 0; q < 16; ++q) {
      float v = p[q];
      v = dpp_add<DPP_XOR1>(v);
      v = dpp_add<DPP_XOR2>(v);
      v = dpp_add<DPP_XOR4>(v);
      v = dpp_add<DPP_XOR8>(v);
      v += __shfl_xor(v, 16);
      p[q] = v;
    }
    if (c == 0) {
      float* outrow = sp + (size_t)(b * 256 + n) * 256 + m0;
      #pragma unroll
      for (int q = 0; q < 16; ++q) {
        int mr = (q & 3) + 8 * (q >> 2) + 4 * hi;
        outrow[mr] = p[q];
      }
      if (mt > nt) {
        #pragma unroll
        for (int q = 0; q < 16; ++q) {
          int mr = (q & 3) + 8 * (q >> 2) + 4 * hi;
          sp[(size_t)(b * 256 + m0 + mr) * 256 + n] = p[q];
        }
      }
    }
  }
}

// -------------------------------------------------------------- colstats ----
// Per-(b,m) column max M and 1/sum(exp(s-M)) over n.
__global__ __launch_bounds__(256) void k_colstats(const float* __restrict__ sp,
                                                  float* __restrict__ colM,
                                                  float* __restrict__ colInv) {
  __shared__ float tile[256][33];
  __shared__ float red[8][32];
  const int t = threadIdx.x;
  const int bb = blockIdx.x >> 3, mt = blockIdx.x & 7;
  const int m0 = mt * 32;
  const int col = t & 31, g = t >> 5;   // g in [0,8)

  for (int cc = 0; cc < 32; ++cc) {
    int nn = cc * 8 + g;
    tile[nn][col] = sp[(size_t)(bb * 256 + nn) * 256 + m0 + col];
  }
  __syncthreads();
  float mx = -1e30f;
  for (int k2 = 0; k2 < 32; ++k2) mx = fmaxf(mx, tile[g * 32 + k2][col]);
  red[g][col] = mx;
  __syncthreads();
  float M = red[0][col];
  #pragma unroll
  for (int j = 1; j < 8; ++j) M = fmaxf(M, red[j][col]);
  float sm = 0.f;
  for (int k2 = 0; k2 < 32; ++k2) sm += __expf(tile[g * 32 + k2][col] - M);
  __syncthreads();
  red[g][col] = sm;
  __syncthreads();
  if (g == 0) {
    float S = red[0][col];
    #pragma unroll
    for (int j = 1; j < 8; ++j) S += red[j][col];
    colM[bb * 256 + m0 + col]   = M;
    colInv[bb * 256 + m0 + col] = 1.0f / S;
  }
}

// -------------------------------------------------------------- aggproj -----
// R18's validated 8-row structure.  att computed on the fly:
// att[n,m] = exp(sp[n,m]-M_m)*inv_m.  BN partials into bnacc via atomics
// (terminal reduction only — R20 lesson).
__global__ __launch_bounds__(256) void k_aggproj(
    const float* __restrict__ x, const float* __restrict__ spRaw,
    const float* __restrict__ colM, const float* __restrict__ colInv,
    const float* __restrict__ W1, const float* __restrict__ b1,
    const float* __restrict__ W2, const float* __restrict__ b2,
    float* __restrict__ out, float* __restrict__ bnacc) {
  __shared__ float att8[8][256];
  __shared__ float xn8[8][256];
  __shared__ float agg8[8][256];
  const int t = threadIdx.x;
  const int bb = blockIdx.x >> 5, ng = blockIdx.x & 31;
  const int n0 = ng * 8;

  const float cm = colM[bb * 256 + t];
  const float ci = colInv[bb * 256 + t];
  #pragma unroll
  for (int i = 0; i < 8; ++i) {
    float s = spRaw[(size_t)(bb * 256 + n0 + i) * 256 + t];
    att8[i][t] = __expf(s - cm) * ci;
    xn8[i][t]  = x[(size_t)(bb * 256 + n0 + i) * 256 + t];
  }
  __syncthreads();

  float ar[8] = {0.f, 0.f, 0.f, 0.f, 0.f, 0.f, 0.f, 0.f};
  for (int m4 = 0; m4 < 64; ++m4) {
    int m = m4 * 4;
    float xv0 = x[(size_t)(bb * 256 + m + 0) * 256 + t];
    float xv1 = x[(size_t)(bb * 256 + m + 1) * 256 + t];
    float xv2 = x[(size_t)(bb * 256 + m + 2) * 256 + t];
    float xv3 = x[(size_t)(bb * 256 + m + 3) * 256 + t];
    #pragma unroll
    for (int i = 0; i < 8; ++i) {
      float4 av = *(const float4*)&att8[i][m];
      ar[i] += av.x * xv0 + av.y * xv1 + av.z * xv2 + av.w * xv3;
    }
  }
  #pragma unroll
  for (int i = 0; i < 8; ++i) agg8[i][t] = ar[i];
  __syncthreads();

  float o[8];
  float bsum = b1[t] + b2[t];
  #pragma unroll
  for (int i = 0; i < 8; ++i) o[i] = bsum;
  for (int d4 = 0; d4 < 64; ++d4) {
    int d = d4 * 4;
    float w10 = W1[(d + 0) * 256 + t], w11 = W1[(d + 1) * 256 + t];
    float w12 = W1[(d + 2) * 256 + t], w13 = W1[(d + 3) * 256 + t];
    float w20 = W2[(d + 0) * 256 + t], w21 = W2[(d + 1) * 256 + t];
    float w22 = W2[(d + 2) * 256 + t], w23 = W2[(d + 3) * 256 + t];
    #pragma unroll
    for (int i = 0; i < 8; ++i) {
      float4 ag = *(const float4*)&agg8[i][d];
      float4 xn = *(const float4*)&xn8[i][d];
      o[i] += ag.x * w10 + ag.y * w11 + ag.z * w12 + ag.w * w13
            + xn.x * w20 + xn.y * w21 + xn.z * w22 + xn.w * w23;
    }
  }
  float s1 = 0.f, s2 = 0.f;
  #pragma unroll
  for (int i = 0; i < 8; ++i) {
    out[(size_t)(bb * 256 + n0 + i) * 256 + t] = o[i];
    s1 += o[i];
    s2 += o[i] * o[i];
  }
  atomicAdd(&bnacc[t], s1);
  atomicAdd(&bnacc[256 + t], s2);
}

// -------------------------------------------------------------- bnapply -----
// grid 2048: one row per block, max TLP on a stream-bound kernel.
__global__ __launch_bounds__(256) void k_bnapply(float* __restrict__ io,
                                                 const float* __restrict__ bnacc,
                                                 const float* __restrict__ gamma,
                                                 const float* __restrict__ beta) {
  const int e = threadIdx.x;
  float mean = bnacc[e] * (1.0f / 2048.0f);
  float var  = bnacc[256 + e] * (1.0f / 2048.0f) - mean * mean;
  float scl  = rsqrtf(var + 1e-5f) * gamma[e];
  float sh   = beta[e] - mean * scl;
  for (int r = blockIdx.x; r < 2048; r += gridDim.x) {
    float v = io[(size_t)r * 256 + e];
    float y = v * scl + sh;
    float s = (y > 0.f) ? 1.0507009873554805f * y
                        : 1.7580993408473766f * (__expf(y) - 1.0f);
    io[(size_t)r * 256 + e] = s;
  }
}

// ---------------------------------------------------------------------------
extern "C" void kernel_launch(void* const* d_in, const int* in_sizes, int n_in,
                              void* d_out, int out_size, void* d_ws, size_t ws_size,
                              hipStream_t stream) {
  const float* x     = (const float*)d_in[0];
  const float* Wp    = (const float*)d_in[1];
  const float* bp    = (const float*)d_in[2];
  const float* watt  = (const float*)d_in[3];
  const float* W1    = (const float*)d_in[4];
  const float* b1    = (const float*)d_in[5];
  const float* W2    = (const float*)d_in[6];
  const float* b2    = (const float*)d_in[7];
  const float* gamma = (const float*)d_in[8];
  const float* beta  = (const float*)d_in[9];
  float* out = (float*)d_out;
  float* ws  = (float*)d_ws;

  float* sp = ws;                                       // 524288 f32 raw scores
  unsigned int* wpfragG = (unsigned int*)(ws + 524288); // 32768 dwords (128 KB)
  unsigned int* xfragG  = wpfragG + 32768;              // 262144 dwords (1 MB)
  float* bnacc  = (float*)(xfragG + 262144);            // 512 f32
  float* colM   = bnacc + 512;                          // 2048 f32
  float* colInv = colM + 2048;                          // 2048 f32

  k_prep    <<<1152, 256, 0, stream>>>(x, Wp, xfragG, wpfragG, bnacc);
  k_scores  <<<256,  512, 0, stream>>>(xfragG, wpfragG, bp, watt, sp);
  k_colstats<<<64,   256, 0, stream>>>(sp, colM, colInv);
  k_aggproj <<<256,  256, 0, stream>>>(x, sp, colM, colInv, W1, b1, W2, b2, out, bnacc);
  k_bnapply <<<2048, 256, 0, stream>>>(out, bnacc, gamma, beta);
}